// Round 13
// baseline (208.871 us; speedup 1.0000x reference)
//
#include <hip/hip_runtime.h>
#include <hip/hip_fp16.h>

typedef __attribute__((ext_vector_type(4))) float f32x4;
typedef __attribute__((ext_vector_type(8))) _Float16 f16x8;
typedef __attribute__((ext_vector_type(2))) _Float16 f16x2;
typedef __attribute__((ext_vector_type(2))) __fp16 fp16x2_raw;
typedef unsigned u32;

union F16X8 { f16x2 p[4]; f16x8 w; };

static __device__ __forceinline__ f16x2 pkrtz(float a, float b) {
    fp16x2_raw r = __builtin_amdgcn_cvt_pkrtz(a, b);
    return __builtin_bit_cast(f16x2, r);
}
static __device__ __forceinline__ f16x2 splat16(unsigned short s) {
    unsigned v = (unsigned)s | ((unsigned)s << 16);
    return __builtin_bit_cast(f16x2, v);
}
static __device__ __forceinline__ void gl_lds16(const float* g, float* l) {
    __builtin_amdgcn_global_load_lds(
        (const __attribute__((address_space(1))) u32*)g,
        (__attribute__((address_space(3))) u32*)l, 16, 0, 0);
}

#define QS 72        // qs16 row stride (shorts): 144B rows, 16B-aligned
#define RING 5       // half-slice (32e x 64f f32 = 8KB) ring slots
#define CNT_OFF 33554432  // counters live at ws + 32MB

// Compute one e-half EH (compile-time 0/1) of slice from ring slot base `so`.
#define COMPUTE_EH(EH, so) do {                                          \
    f16x8 bb[2];                                                         \
    _Pragma("unroll") for (int Nt = 0; Nt < 2; ++Nt) {                   \
        F16X8 bu;                                                        \
        _Pragma("unroll") for (int jj = 0; jj < 4; ++jj) {               \
            int e0 = kg * 8 + 2 * jj;                                    \
            float v0 = ring[(so) + e0 * 64 + fcol + Nt * 16];            \
            float v1 = ring[(so) + (e0 + 1) * 64 + fcol + Nt * 16];      \
            bu.p[jj] = pkrtz(v0, v1);                                    \
        }                                                                \
        bb[Nt] = bu.w;                                                   \
    }                                                                    \
    _Pragma("unroll") for (int Mt = 0; Mt < 4; ++Mt) {                   \
        F16X8 au;                                                        \
        _Pragma("unroll") for (int h = 0; h < 4; ++h)                    \
            au.p[h] = sh[Mt] * u[Mt][EH][h];                             \
        acc[Mt][0] = __builtin_amdgcn_mfma_f32_16x16x32_f16(au.w, bb[0], acc[Mt][0], 0, 0, 0); \
        acc[Mt][1] = __builtin_amdgcn_mfma_f32_16x16x32_f16(au.w, bb[1], acc[Mt][1], 0, 0, 0); \
    }                                                                    \
} while (0)

#define WAIT_BAR_ISSUE(hs) do {                                          \
    asm volatile("s_waitcnt vmcnt(3)" ::: "memory");                     \
    __builtin_amdgcn_s_barrier();                                        \
    asm volatile("" ::: "memory");                                       \
    if ((hs) + 4 < 32)                                                   \
        gl_lds16(Sst + (size_t)((hs) + 4) * 2048 + w * 256 + lane * 4,   \
                 &ring[(((hs) + 4) % RING) * 2048 + w * 256]);           \
} while (0)

__global__ __launch_bounds__(512, 4) void quad_k1(
    const float* __restrict__ q, const float* __restrict__ kv,
    float* __restrict__ out, float* __restrict__ wsp, int* __restrict__ cnt)
{
    __shared__ unsigned short qs16[256 * QS];          // 36864 B f16(q/8)
    __shared__ __align__(16) float ring[RING * 2048];  // 40960 B
    __shared__ int lds_old;

    const int tid = threadIdx.x;
    // d-quarter split: WG owns a CONTIGUOUS 256KB of S, read exactly once chip-wide.
    const int wg = blockIdx.x;             // 0..511
    const int xcd = wg & 7, p = wg >> 3;
    const int chunk = xcd * 16 + (p >> 2); // 0..127 ; 4 dq-siblings same XCD
    const int dq = p & 3;

    const int lane = tid & 63;
    const int w = tid >> 6;                // 8 waves: cq = w>>1 (64-row band), fh = w&1
    const int cq = w >> 1, fh = w & 1;
    const int ra = lane & 15, kg = lane >> 4;
    const int fcol = fh * 32 + ra;

    const float* qch = q  + (size_t)chunk * 16384;
    const float* Sst = kv + (size_t)chunk * 262144 + (size_t)dq * 65536;

    // ---- stage q chunk (256x64) -> LDS f16, scaled 0.125 (exact) ----
#pragma unroll
    for (int i = 0; i < 8; ++i) {
        int idx4 = i * 512 + tid;            // f32x4 index 0..4095
        int row = idx4 >> 4, col4 = idx4 & 15;
        f32x4 v = *(const f32x4*)(qch + idx4 * 4);
        v *= 0.125f;
        f16x2 h0 = pkrtz(v[0], v[1]);
        f16x2 h1 = pkrtz(v[2], v[3]);
        unsigned pair[2] = { __builtin_bit_cast(unsigned, h0),
                             __builtin_bit_cast(unsigned, h1) };
        *(unsigned long long*)&qs16[row * QS + col4 * 4] = *(unsigned long long*)pair;
    }
    __syncthreads();

    // ---- prologue DMA: half-slices 0..3 (each wave contributes 1KB/half-slice) ----
#pragma unroll
    for (int s = 0; s < 4; ++s)
        gl_lds16(Sst + (size_t)s * 2048 + w * 256 + lane * 4, &ring[s * 2048 + w * 256]);

    // ---- hoisted A e-fragments u[Mt][eh][h] ----
    f16x2 u[4][2][4];
#pragma unroll
    for (int Mt = 0; Mt < 4; ++Mt)
#pragma unroll
        for (int eh = 0; eh < 2; ++eh) {
            F16X8 t;
            t.w = *(const f16x8*)&qs16[(cq * 64 + Mt * 16 + ra) * QS + eh * 32 + kg * 8];
#pragma unroll
            for (int h = 0; h < 4; ++h) u[Mt][eh][h] = t.p[h];
        }

    f32x4 acc[4][2] = {};
    f16x2 sh[4];

    // ---- main: 14 slice-pairs with counted vmcnt + 1 barrier per half-slice ----
#pragma unroll 1
    for (int sl = 0; sl < 14; ++sl) {
#pragma unroll
        for (int Mt = 0; Mt < 4; ++Mt)
            sh[Mt] = splat16(qs16[(cq * 64 + Mt * 16 + ra) * QS + dq * 16 + sl]);
        const int hs0 = sl * 2;
        WAIT_BAR_ISSUE(hs0);
        COMPUTE_EH(0, (hs0 % RING) * 2048);
        WAIT_BAR_ISSUE(hs0 + 1);
        COMPUTE_EH(1, ((hs0 + 1) % RING) * 2048);
    }
    // ---- tail: drain once, then barrier-free (slices 14,15 = hs 28..31) ----
    asm volatile("s_waitcnt vmcnt(0)" ::: "memory");
    __builtin_amdgcn_s_barrier();
    asm volatile("" ::: "memory");
#pragma unroll
    for (int sl = 14; sl < 16; ++sl) {
#pragma unroll
        for (int Mt = 0; Mt < 4; ++Mt)
            sh[Mt] = splat16(qs16[(cq * 64 + Mt * 16 + ra) * QS + dq * 16 + sl]);
        const int hs0 = sl * 2;
        COMPUTE_EH(0, (hs0 % RING) * 2048);
        COMPUTE_EH(1, ((hs0 + 1) % RING) * 2048);
    }

    // ---- write partial tile ----
    float* pws = wsp + (size_t)(chunk * 4 + dq) * 16384;
#pragma unroll
    for (int Mt = 0; Mt < 4; ++Mt)
#pragma unroll
        for (int Nt = 0; Nt < 2; ++Nt)
#pragma unroll
            for (int j = 0; j < 4; ++j)
                pws[(cq * 64 + Mt * 16 + kg * 4 + j) * 64 + fh * 32 + Nt * 16 + ra] =
                    acc[Mt][Nt][j];

    // ---- last WG of the chunk reduces 4 partials -> out ----
    __threadfence();
    __syncthreads();
    if (tid == 0) lds_old = atomicAdd(&cnt[chunk], 1);
    __syncthreads();
    if (lds_old == 3) {
        __threadfence();
        const f32x4* p0 = (const f32x4*)(wsp + (size_t)chunk * 4 * 16384);
        f32x4* o4 = (f32x4*)(out + (size_t)chunk * 16384);
#pragma unroll
        for (int i = 0; i < 8; ++i) {
            int idx4 = i * 512 + tid;          // 0..4095
            f32x4 v = p0[idx4] + p0[idx4 + 4096] + p0[idx4 + 8192] + p0[idx4 + 12288];
            o4[idx4] = 0.5f * v;
        }
    }
}

extern "C" void kernel_launch(void* const* d_in, const int* in_sizes, int n_in,
                              void* d_out, int out_size, void* d_ws, size_t ws_size,
                              hipStream_t stream) {
    const float* q  = (const float*)d_in[0];
    const float* kv = (const float*)d_in[1];
    float* out = (float*)d_out;
    float* wsp = (float*)d_ws;
    int* cnt = (int*)((char*)d_ws + CNT_OFF);
    hipMemsetAsync(cnt, 0, 128 * sizeof(int), stream);
    hipLaunchKernelGGL(quad_k1, dim3(512), dim3(512), 0, stream, q, kv, out, wsp, cnt);
}

// Round 14
// 41.467 us; speedup vs baseline: 5.0371x; 5.0371x over previous
//
#include <hip/hip_runtime.h>
#include <hip/hip_fp16.h>

typedef __attribute__((ext_vector_type(4))) float f32x4;
typedef __attribute__((ext_vector_type(8))) _Float16 f16x8;
typedef __attribute__((ext_vector_type(2))) _Float16 f16x2;
typedef __attribute__((ext_vector_type(2))) __fp16 fp16x2_raw;

union F16X8 { f16x2 p[4]; f16x8 w; };

static __device__ __forceinline__ f16x2 pkrtz(float a, float b) {
    fp16x2_raw r = __builtin_amdgcn_cvt_pkrtz(a, b);  // v_cvt_pkrtz_f16_f32
    return __builtin_bit_cast(f16x2, r);
}
static __device__ __forceinline__ f16x2 splat16(unsigned short s) {
    unsigned v = (unsigned)s | ((unsigned)s << 16);
    return __builtin_bit_cast(f16x2, v);
}

#define QS 72   // qs16 row stride (shorts): 144B rows, 16B-aligned

// Load B-fragment for slice dd: 16 coalesced dwords, 4x64B segments per inst.
// Each wave streams its OWN f-slab (no duplication). sched_barrier(0) pins the
// loads (R9/R11 de-pipelining countermeasure; R10 proof: VGPR 88, pipeline held).
#define LOADB(BUF, dd) do {                                           \
    const float* _p = Sb + (size_t)(dd) * 4096;                       \
    _Pragma("unroll") for (int _K = 0; _K < 2; ++_K)                  \
    _Pragma("unroll") for (int _j = 0; _j < 8; ++_j)                  \
        b##BUF[_K][_j] = _p[_K * 2048 + _j * 64];                     \
    __builtin_amdgcn_sched_barrier(0);                                \
} while (0)

// Compute slice dd: convert B to f16, A = s_d (f16 LDS broadcast) * u_e, 8 MFMA.
#define COMPUTE(BUF, dd) do {                                         \
    f16x8 _bb[2];                                                     \
    _Pragma("unroll") for (int _K = 0; _K < 2; ++_K) {                \
        F16X8 _bu;                                                    \
        _Pragma("unroll") for (int _h = 0; _h < 4; ++_h)              \
            _bu.p[_h] = pkrtz(b##BUF[_K][2*_h], b##BUF[_K][2*_h+1]);  \
        _bb[_K] = _bu.w;                                              \
    }                                                                 \
    _Pragma("unroll") for (int _M = 0; _M < 4; ++_M) {                \
        f16x2 _sh = splat16(qs16[(_M * 16 + ra) * QS + (dd)]);        \
        _Pragma("unroll") for (int _K = 0; _K < 2; ++_K) {            \
            F16X8 _au;                                                \
            _Pragma("unroll") for (int _h = 0; _h < 4; ++_h)          \
                _au.p[_h] = _sh * u[_M][_K][_h];                      \
            acc[_M] = __builtin_amdgcn_mfma_f32_16x16x32_f16(_au.w, _bb[_K], acc[_M], 0, 0, 0); \
        }                                                             \
    }                                                                 \
} while (0)

__global__ __launch_bounds__(256, 2) void quad_form_kernel(
    const float* __restrict__ q, const float* __restrict__ kv, float* __restrict__ out)
{
    __shared__ unsigned short qs16[64 * QS];   // 9216 B: f16(q*0.125), WG's 64 rows

    const int tid = threadIdx.x;

    // c-quarter split: WG = 64 c-rows x all 64 f. Wave w owns f-slab w*16 (disjoint
    // 256KB S stream -> zero intra-WG duplication). The 4 c-sibling WGs of a chunk
    // read identical S lines; XCD swizzle puts them on one XCD -> L2 absorbs.
    const int wg = blockIdx.x;             // 0..511
    const int xcd = wg & 7, p = wg >> 3;   // p 0..63
    const int chunk = xcd * 16 + (p >> 2); // 0..127
    const int cq = p & 3;

    const int lane = tid & 63;
    const int w = tid >> 6;                // wave -> f-slab w*16
    const int ra = lane & 15, kg = lane >> 4;

    const float* qch = q  + (size_t)chunk * 16384 + cq * 4096;   // 64 rows x 64
    const float* Sch = kv + (size_t)chunk * 262144;
    float*       och = out + (size_t)chunk * 16384 + cq * 4096;

    // ---- stage q quarter (64x64) -> LDS f16, scaled by 0.125 (exact) ----
#pragma unroll
    for (int i = 0; i < 4; ++i) {
        int idx4 = i * 256 + tid;            // f32x4 index 0..1023
        int row = idx4 >> 4, col4 = idx4 & 15;
        f32x4 v = *(const f32x4*)(qch + idx4 * 4);
        v *= 0.125f;
        f16x2 h0 = pkrtz(v[0], v[1]);
        f16x2 h1 = pkrtz(v[2], v[3]);
        unsigned pair[2] = { __builtin_bit_cast(unsigned, h0),
                             __builtin_bit_cast(unsigned, h1) };
        *(unsigned long long*)&qs16[row * QS + col4 * 4] =
            *(unsigned long long*)pair;      // ds_write_b64
    }
    __syncthreads();   // only barrier; qs16 read-only afterwards

    // per-lane base: wave-private f-slab
    const float* Sb = Sch + kg * 512 + w * 16 + ra;   // + d*4096 + K*2048 + j*64

    // ---- hoisted A e-fragments u[Mt][Ks][h] (f16, pre-scaled); same for all waves ----
    f16x2 u[4][2][4];
#pragma unroll
    for (int Mt = 0; Mt < 4; ++Mt)
#pragma unroll
        for (int Ks = 0; Ks < 2; ++Ks) {
            F16X8 t;
            t.w = *(const f16x8*)&qs16[(Mt * 16 + ra) * QS + Ks * 32 + kg * 8];
#pragma unroll
            for (int h = 0; h < 4; ++h) u[Mt][Ks][h] = t.p[h];
        }

    f32x4 acc[4] = {};
    float bA[2][8], bB[2][8], bC[2][8], bD[2][8];  // 4-deep rotation (R10-proven)

    LOADB(A, 0); LOADB(B, 1); LOADB(C, 2); LOADB(D, 3);

#pragma unroll 1
    for (int it = 0; it < 16; ++it) {      // 16 iters x 4 slices = 64
        const int d = it * 4;
        COMPUTE(A, d);     if (d + 4 < 64) LOADB(A, d + 4);
        COMPUTE(B, d + 1); if (d + 5 < 64) LOADB(B, d + 5);
        COMPUTE(C, d + 2); if (d + 6 < 64) LOADB(C, d + 6);
        COMPUTE(D, d + 3); if (d + 7 < 64) LOADB(D, d + 7);
    }

    // ---- epilogue: out = 0.5 * acc ----
#pragma unroll
    for (int Mt = 0; Mt < 4; ++Mt)
#pragma unroll
        for (int j = 0; j < 4; ++j)
            och[(Mt * 16 + kg * 4 + j) * 64 + w * 16 + ra] = 0.5f * acc[Mt][j];
}

extern "C" void kernel_launch(void* const* d_in, const int* in_sizes, int n_in,
                              void* d_out, int out_size, void* d_ws, size_t ws_size,
                              hipStream_t stream) {
    const float* q  = (const float*)d_in[0];
    const float* kv = (const float*)d_in[1];
    float* out = (float*)d_out;
    hipLaunchKernelGGL(quad_form_kernel, dim3(512), dim3(256), 0, stream, q, kv, out);
}